// Round 1
// 29.324 us; speedup vs baseline: 1.0852x; 1.0852x over previous
//
#include <hip/hip_runtime.h>
#include <stdint.h>

#define NPIX  (512 * 512)
#define NB    8
#define NCH   32                 // fine-hist chunks per batch
#define CHPX  (NPIX / NCH)       // 8192 px per chunk (u16 cell counts can't overflow)
#define FB    128                // fine bins per axis (2 per coarse bin)
#define MPW   161                // padded mid row width: 16 guard + 128 + 17 guard
#define HDR_FLOATS 1024          // ws: [0,512) minmax partials, [512,520) mi, 520 cnt

typedef __attribute__((ext_vector_type(4))) unsigned uint4v;
typedef __attribute__((ext_vector_type(4))) float    float4v;

// 33-tap Gaussian conv kernel, w[k] = exp(-(16-k)^2/8)  (sigma=1 bin, fine=1/2 bin)
__device__ constexpr float WK[33] = {
  1.2664166e-14f, 6.1019365e-13f, 2.2897490e-11f, 6.6915858e-10f,
  1.5229979e-08f, 2.6995785e-07f, 3.7266532e-06f, 4.0065297e-05f,
  3.3546263e-04f, 2.1874911e-03f, 1.1108997e-02f, 4.3936934e-02f,
  1.3533528e-01f, 3.2465247e-01f, 6.0653066e-01f, 8.8249690e-01f,
  1.0f,
  8.8249690e-01f, 6.0653066e-01f, 3.2465247e-01f, 1.3533528e-01f,
  4.3936934e-02f, 1.1108997e-02f, 2.1874911e-03f, 3.3546263e-04f,
  4.0065297e-05f, 3.7266532e-06f, 2.6995785e-07f, 1.5229979e-08f,
  6.6915858e-10f, 2.2897490e-11f, 6.1019365e-13f, 1.2664166e-14f
};

// ---- kernel 1: per-block min/max partials (also re-arms the tail counter) ----
__global__ __launch_bounds__(1024) void minmax_kernel(const float* __restrict__ pred,
                                                      const float* __restrict__ tgt,
                                                      float2* __restrict__ mm,
                                                      unsigned* __restrict__ cnt) {
  __shared__ float smin[16], smax[16];
  const int tid = threadIdx.x, lane = tid & 63, wave = tid >> 6;
  if (blockIdx.x == 0 && tid == 0) cnt[0] = 0u;   // re-armed every launch/replay
  const int pair = blockIdx.x >> 4, sub = blockIdx.x & 15;
  const float* src = pair < 8 ? pred + (size_t)pair * NPIX
                              : tgt  + (size_t)(pair - 8) * NPIX;
  const float4v* s4 = (const float4v*)src + sub * 4096;
  float vmin = 3.0e38f, vmax = -3.0e38f;
  #pragma unroll
  for (int k = 0; k < 4; ++k) {
    float4v v = s4[k * 1024 + tid];
    vmin = fminf(vmin, fminf(fminf(v[0], v[1]), fminf(v[2], v[3])));
    vmax = fmaxf(vmax, fmaxf(fmaxf(v[0], v[1]), fmaxf(v[2], v[3])));
  }
  #pragma unroll
  for (int off = 32; off; off >>= 1) {
    vmin = fminf(vmin, __shfl_xor(vmin, off));
    vmax = fmaxf(vmax, __shfl_xor(vmax, off));
  }
  if (lane == 0) { smin[wave] = vmin; smax[wave] = vmax; }
  __syncthreads();
  if (tid == 0) {
    float m = smin[0], M = smax[0];
    #pragma unroll
    for (int w = 1; w < 16; ++w) { m = fminf(m, smin[w]); M = fmaxf(M, smax[w]); }
    mm[blockIdx.x] = (float2){m, M};
  }
}

// ---- kernel 2: 2D fine histogram (128x128) per (batch, chunk) ----
// NB*NCH = 256 blocks x 512 thr. LDS: 8192 u32 words, 2 u16 cells per word.
// Bank-swizzled cell addressing: w ^= (fp&7)<<2 spreads center-heavy ft bins
// across all 32 banks; flush un-permutes (contiguous per 16-lane group), so
// the global layout is unchanged.
__global__ __launch_bounds__(512) void fine_hist_kernel(const float* __restrict__ pred,
                                                        const float* __restrict__ tgt,
                                                        const float2* __restrict__ mm,
                                                        unsigned* __restrict__ part) {
  __shared__ unsigned H[FB * FB / 2];   // 32KB
  const int tid = threadIdx.x;
  const int b = blockIdx.x >> 5, c = blockIdx.x & 31;

  float pmin = 3.0e38f, pmax = -3.0e38f, tmin = 3.0e38f, tmax = -3.0e38f;
  #pragma unroll
  for (int s2 = 0; s2 < 16; ++s2) {
    float2 a = mm[b * 16 + s2], d = mm[(8 + b) * 16 + s2];
    pmin = fminf(pmin, a.x); pmax = fmaxf(pmax, a.y);
    tmin = fminf(tmin, d.x); tmax = fmaxf(tmax, d.y);
  }
  // fine index f = round(t*2), t = 63*(x-min)/(range+eps):  f = x*sp + op
  const float sp = 126.0f / (pmax - pmin + 1e-10f), op = -pmin * sp + 0.5f;
  const float st = 126.0f / (tmax - tmin + 1e-10f), ot = -tmin * st + 0.5f;

  #pragma unroll
  for (int j = 0; j < 4; ++j)
    ((uint4v*)H)[j * 512 + tid] = (uint4v){0u, 0u, 0u, 0u};
  __syncthreads();

  const float4v* p4 = (const float4v*)(pred + (size_t)b * NPIX + (size_t)c * CHPX);
  const float4v* t4 = (const float4v*)(tgt  + (size_t)b * NPIX + (size_t)c * CHPX);
  #pragma unroll
  for (int it = 0; it < 4; ++it) {
    float4v vp = p4[it * 512 + tid];
    float4v vt = t4[it * 512 + tid];
    #pragma unroll
    for (int j = 0; j < 4; ++j) {
      int fp = (int)(vp[j] * sp + op);      // 0..126
      int ft = (int)(vt[j] * st + ot);
      int w  = (fp << 6) | (ft >> 1);
      atomicAdd(&H[w ^ ((fp & 7) << 2)], 1u << ((ft & 1) << 4));
    }
  }
  __syncthreads();

  uint4v* dst = (uint4v*)(part + ((size_t)blockIdx.x << 13));
  #pragma unroll
  for (int j = 0; j < 4; ++j) {
    int g = j * 512 + tid;                  // uint4 index; word base = 4g
    dst[g] = ((uint4v*)H)[g ^ ((g >> 4) & 7)];   // un-swizzle: same XOR const per 16 lanes
  }
}

// ---- kernel 3: sum 32 chunk partials -> f32 fine histogram [128][128] ----
__global__ __launch_bounds__(256) void reduce_fine_kernel(const unsigned* __restrict__ part,
                                                          float2* __restrict__ fineF) {
  const int tid = threadIdx.x;
  const int b = blockIdx.x >> 5, sl = blockIdx.x & 31;
  const int w = sl * 256 + tid;                       // word in [0, 8192)
  const unsigned* src = part + ((size_t)b << 18) + w;
  unsigned lo = 0, hi = 0;
  #pragma unroll 8
  for (int c = 0; c < 32; ++c) {
    unsigned v = src[(size_t)c << 13];
    lo += v & 0xFFFFu; hi += v >> 16;
  }
  float2 o; o.x = (float)lo; o.y = (float)hi;
  fineF[(size_t)b * 8192 + w] = o;                    // fineG[b][128][128] flat
}

// ---- kernel 4 (fused): conv1 (fine-p axis, decimate x2) -> mid in LDS ->
//      conv2 (fine-t axis) -> marginals -> MI -> last-block final mean ----
// NB = 8 blocks x 1024 thr. Phase A: thread (r=tid>>7, ft=tid&127) holds a
// 47-row register window of fineG column ft, emits 8 mid rows (identical FP
// op order to the old conv1). mid lives only in LDS (no global roundtrip).
// Phase B is the old conv2mi. Final mean: device-scope atomics + counter;
// counter re-armed by minmax each launch and self-reset here (replay-safe).
__global__ __launch_bounds__(1024) void tail_kernel(const float* __restrict__ fineG,
                                                    float* __restrict__ mi,
                                                    unsigned* __restrict__ cnt,
                                                    float* __restrict__ out) {
  __shared__ float S[14608];   // [0,10304) mid[64][161] | [10304,14464) pxy[64][65]
                               // | 14464 px | 14528 py | 14592 wred
  const int tid = threadIdx.x, lane = tid & 63, wave = tid >> 6;
  const int b = blockIdx.x;

  // ---- phase A: conv along fine-p rows, decimate x2 -> S[0,10304) ----
  {
    const int ft = tid & 127, r = tid >> 7;
    const float* fb = fineG + ((size_t)b << 14) + ft;
    float v[47];
    #pragma unroll
    for (int t = 0; t < 47; ++t) {
      int fp = 16 * r - 16 + t;
      v[t] = ((unsigned)fp < 128u) ? fb[fp << 7] : 0.0f;
    }
    float acc[8];
    #pragma unroll
    for (int d = 0; d < 8; ++d) {
      float a = 0.0f;
      #pragma unroll
      for (int k = 0; k < 33; ++k) a += WK[k] * v[2 * d + k];
      acc[d] = a;
    }
    #pragma unroll
    for (int d = 0; d < 8; ++d)
      S[(8 * r + d) * MPW + ft + 16] = acc[d];
    // zero guard columns: 64 rows x (16 left + 17 right)
    #pragma unroll
    for (int ii = 0; ii < 3; ++ii) {
      int idx = ii * 1024 + tid;
      if (idx < 64 * 33) {
        int rr = idx / 33, cc = idx % 33;
        int col = cc < 16 ? cc : cc + 128;
        S[rr * MPW + col] = 0.0f;
      }
    }
  }
  __syncthreads();

  // ---- phase B: conv along fine-t axis -> pxy ----
  const int i = tid & 63, js = (tid >> 6) << 2;
  {
    float v[39];
    #pragma unroll
    for (int t = 0; t < 39; ++t) v[t] = S[i * MPW + 2 * js + t];
    float acc[4] = {0.0f, 0.0f, 0.0f, 0.0f};
    #pragma unroll
    for (int d = 0; d < 4; ++d)
      #pragma unroll
      for (int k = 0; k < 33; ++k) acc[d] += WK[k] * v[2 * d + k];
    const float invN = 1.0f / (float)NPIX;
    #pragma unroll
    for (int d = 0; d < 4; ++d) S[10304 + i * 65 + js + d] = acc[d] * invN;
  }
  __syncthreads();

  // marginals: wave w owns 4 rows + 4 cols (16-lane groups)
  {
    const int l16 = lane & 15, sub16 = lane >> 4;
    int row = 4 * wave + sub16;
    float s = 0.0f;
    #pragma unroll
    for (int k = 0; k < 4; ++k) s += S[10304 + row * 65 + l16 * 4 + k];
    #pragma unroll
    for (int off = 8; off; off >>= 1) s += __shfl_xor(s, off);
    if (l16 == 0) S[14464 + row] = s;     // px
    float t2 = 0.0f;
    #pragma unroll
    for (int k = 0; k < 4; ++k) t2 += S[10304 + (l16 * 4 + k) * 65 + row];
    #pragma unroll
    for (int off = 8; off; off >>= 1) t2 += __shfl_xor(t2, off);
    if (l16 == 0) S[14528 + row] = t2;    // py
  }
  __syncthreads();

  float a = 0.0f;
  #pragma unroll
  for (int r = 0; r < 4; ++r) {
    int e = r * 1024 + tid;
    int ii = e >> 6, jj = e & 63;
    float pv = S[10304 + ii * 65 + jj];
    float d = S[14464 + ii] * S[14528 + jj] + 1e-10f;
    a += pv * __logf((pv + 1e-10f) / d);
  }
  #pragma unroll
  for (int off = 32; off; off >>= 1) a += __shfl_xor(a, off);
  if (lane == 0) S[14592 + wave] = a;
  __syncthreads();

  if (tid == 0) {
    float s = 0.0f;
    #pragma unroll
    for (int w = 0; w < 16; ++w) s += S[14592 + w];
    atomicExch(&mi[b], s);                 // device-scope atomic store
    __threadfence();                       // release: mi visible before counter
    unsigned prev = atomicAdd(cnt, 1u);
    if (prev == NB - 1) {                  // last block finalizes
      __threadfence();                     // acquire
      float tot = 0.0f;
      #pragma unroll
      for (int k = 0; k < NB; ++k) tot += atomicAdd(&mi[k], 0.0f);  // atomic read
      out[0] = -(tot * (1.0f / NB));
      atomicExch(cnt, 0u);                 // self-reset (rocprof replay safety)
    }
  }
}

extern "C" void kernel_launch(void* const* d_in, const int* in_sizes, int n_in,
                              void* d_out, int out_size, void* d_ws, size_t ws_size,
                              hipStream_t stream) {
  const float* pred = (const float*)d_in[0];
  const float* tgt  = (const float*)d_in[1];
  float*    out  = (float*)d_out;
  float*    wsf  = (float*)d_ws;
  float2*   mm   = (float2*)d_ws;                      // 256 float2 in [0,512) floats
  float*    mi   = wsf + 512;                          // 8 floats
  unsigned* cnt  = (unsigned*)(wsf + 520);             // tail completion counter
  unsigned* part = (unsigned*)(wsf + HDR_FLOATS);      // NB*NCH*8192 words = 8MB
  float*    fineG = wsf + HDR_FLOATS + (size_t)NB * NCH * 8192;   // NB*16384 f32

  minmax_kernel     <<<256,      1024, 0, stream>>>(pred, tgt, mm, cnt);
  fine_hist_kernel  <<<NB * NCH,  512, 0, stream>>>(pred, tgt, mm, part);
  reduce_fine_kernel<<<256,       256, 0, stream>>>(part, (float2*)fineG);
  tail_kernel       <<<NB,       1024, 0, stream>>>(fineG, mi, cnt, out);
}